// Round 1
// baseline (180.531 us; speedup 1.0000x reference)
//
#include <hip/hip_runtime.h>

#define HH 260
#define WW 346
#define CC 1212            // 2H + 2W
#define BB 16
#define TT 4096
#define INV_TEMP (1.0f/256.0f)
#define KCH 128            // chunks per batch
#define LCH (TT / KCH)     // 32 steps per chunk
#define BLK 128            // threads per block (phases 1 & 3)
#define NJ ((CC + BLK - 1) / BLK)   // 10 channels per thread

// ---------------- Phase 1: per-chunk local state (zero carry) ----------------
__global__ __launch_bounds__(BLK) void p1_local(const float* __restrict__ target,
                                                float* __restrict__ Lbuf) {
    const int blk = blockIdx.x;
    const int b = blk / KCH, k = blk % KCH;
    const int a = k * LCH, e = a + LCH;
    const int tid = threadIdx.x;

    __shared__ float tg[LCH][4];
    __shared__ float tnext;
    for (int idx = tid; idx < LCH * 4; idx += BLK)
        tg[idx >> 2][idx & 3] = target[((size_t)b * TT + a) * 4 + idx];
    if (tid == 0) tnext = (e < TT) ? target[((size_t)b * TT + e) * 4] : 0.0f;
    __syncthreads();

    float s[NJ];
#pragma unroll
    for (int j = 0; j < NJ; ++j) s[j] = 0.0f;

    for (int i = e - 1; i >= a; --i) {
        const int li = i - a;
        const float ti = tg[li][0];
        const float tn = (li == LCH - 1) ? tnext : tg[li + 1][0];
        const float d = (i >= TT - 1) ? 0.0f : __expf(-(tn - ti) * INV_TEMP);
        const int y = (int)tg[li][1], x = (int)tg[li][2], p = (int)tg[li][3];
        const int yc = p * HH + y;
        const int xc = 2 * HH + p * WW + x;
#pragma unroll
        for (int j = 0; j < NJ; ++j) {
            const int c = tid + j * BLK;
            const float add = (c == yc ? 1.0f : 0.0f) + (c == xc ? 1.0f : 0.0f);
            s[j] = fmaf(s[j], d, add);
        }
    }

    const size_t base = ((size_t)b * KCH + k) * CC;
#pragma unroll
    for (int j = 0; j < NJ; ++j) {
        const int c = tid + j * BLK;
        if (c < CC) Lbuf[base + c] = s[j];
    }
}

// ------- Phase 2: sequential chunk combine -> carry_in per chunk (in place) -------
__global__ void p2_carry(const float* __restrict__ target, float* __restrict__ Lbuf) {
    const int gid = blockIdx.x * blockDim.x + threadIdx.x;
    if (gid >= BB * CC) return;
    const int b = gid / CC, c = gid % CC;
    float carry = 0.0f;   // carry_in(K-1) = 0
    for (int k = KCH - 1; k >= 0; --k) {
        const size_t idx = ((size_t)b * KCH + k) * CC + c;
        const float L = Lbuf[idx];
        Lbuf[idx] = carry;               // store carry_in(k)
        float P = 0.0f;
        if (k < KCH - 1) {
            const int a = k * LCH, e = a + LCH;
            const float ta = target[((size_t)b * TT + a) * 4];
            const float te = target[((size_t)b * TT + e) * 4];
            P = __expf(-(te - ta) * INV_TEMP);
        }
        carry = fmaf(P, carry, L);       // S_k = L_k + P_k * carry_in(k)
    }
}

// ---------------- Phase 3: replay with true carry + fused loss ----------------
__global__ __launch_bounds__(BLK) void p3_loss(const float* __restrict__ pred,
                                               const float* __restrict__ target,
                                               const float* __restrict__ carryBuf,
                                               double* __restrict__ partials) {
    const int blk = blockIdx.x;
    const int b = blk / KCH, k = blk % KCH;
    const int a = k * LCH, e = a + LCH;
    const int tid = threadIdx.x;
    const int wave = tid >> 6, lane = tid & 63;

    __shared__ float tg[LCH][4];
    __shared__ float tnext;
    __shared__ float red[BLK / 64][6];

    for (int idx = tid; idx < LCH * 4; idx += BLK)
        tg[idx >> 2][idx & 3] = target[((size_t)b * TT + a) * 4 + idx];
    if (tid == 0) tnext = (e < TT) ? target[((size_t)b * TT + e) * 4] : 0.0f;

    float s[NJ];
    const size_t cbase = ((size_t)b * KCH + k) * CC;
#pragma unroll
    for (int j = 0; j < NJ; ++j) {
        const int c = tid + j * BLK;
        s[j] = (c < CC) ? carryBuf[cbase + c] : 0.0f;
    }
    __syncthreads();

    double lacc = 0.0;  // thread 0 only
    for (int i = e - 1; i >= a; --i) {
        const int li = i - a;
        const float ti = tg[li][0];
        const float tn = (li == LCH - 1) ? tnext : tg[li + 1][0];
        const float d = (i == 0 || i >= TT - 1) ? 0.0f : __expf(-(tn - ti) * INV_TEMP);
        const int y = (int)tg[li][1], x = (int)tg[li][2], p = (int)tg[li][3];
        const int yc = p * HH + y;
        const int xc = 2 * HH + p * WW + x;

#pragma unroll
        for (int j = 0; j < NJ; ++j) {
            const int c = tid + j * BLK;
            const float add = (c == yc ? 1.0f : 0.0f) + (c == xc ? 1.0f : 0.0f);
            s[j] = fmaf(s[j], d, add);
        }

        // active segments for this position's polarity
        const int y0 = p * HH;            // y-segment [y0, y0+H)
        const int x0 = 2 * HH + p * WW;   // x-segment [x0, x0+W)
        float zp_y = 0.f, zs_y = 0.f, dt_y = 0.f;
        float zp_x = 0.f, zs_x = 0.f, dt_x = 0.f;
        const float* __restrict__ prow = pred + ((size_t)b * TT + i) * CC;
#pragma unroll
        for (int j = 0; j < NJ; ++j) {
            const int c = tid + j * BLK;
            if (c < CC) {
                const float sv = s[j];
                const unsigned dy = (unsigned)(c - y0);
                const unsigned dx = (unsigned)(c - x0);
                if (dy < (unsigned)HH) {
                    const float pr = prow[c];
                    const float es = __expf(sv);
                    zp_y += __expf(pr);
                    zs_y += es;
                    dt_y = fmaf(es, pr, dt_y);
                } else if (dx < (unsigned)WW) {
                    const float pr = prow[c];
                    const float es = __expf(sv);
                    zp_x += __expf(pr);
                    zs_x += es;
                    dt_x = fmaf(es, pr, dt_x);
                }
            }
        }
        // 64-lane butterfly reduce of the 6 partials
#pragma unroll
        for (int off = 32; off > 0; off >>= 1) {
            zp_y += __shfl_xor(zp_y, off);
            zs_y += __shfl_xor(zs_y, off);
            dt_y += __shfl_xor(dt_y, off);
            zp_x += __shfl_xor(zp_x, off);
            zs_x += __shfl_xor(zs_x, off);
            dt_x += __shfl_xor(dt_x, off);
        }
        if (lane == 0) {
            red[wave][0] = zp_y; red[wave][1] = zs_y; red[wave][2] = dt_y;
            red[wave][3] = zp_x; red[wave][4] = zs_x; red[wave][5] = dt_x;
        }
        __syncthreads();
        if (tid == 0) {
            float Zpy = 0.f, Zsy = 0.f, Dy = 0.f, Zpx = 0.f, Zsx = 0.f, Dx = 0.f;
#pragma unroll
            for (int w = 0; w < BLK / 64; ++w) {
                Zpy += red[w][0]; Zsy += red[w][1]; Dy += red[w][2];
                Zpx += red[w][3]; Zsx += red[w][4]; Dx += red[w][5];
            }
            const float loss = __logf(Zpy) + __logf(Zpx) - Dy / Zsy - Dx / Zsx;
            lacc += (double)loss;
        }
        __syncthreads();   // protect red[] before next step
    }
    if (tid == 0) partials[blk] = lacc;
}

// ---------------- Finalize: deterministic reduction of block partials ----------------
__global__ void p4_final(const double* __restrict__ partials, float* __restrict__ out) {
    const int tid = threadIdx.x;   // 256
    double sum = 0.0;
    for (int i = tid; i < BB * KCH; i += 256) sum += partials[i];
#pragma unroll
    for (int off = 32; off > 0; off >>= 1) sum += __shfl_xor(sum, off);
    __shared__ double sred[4];
    const int wave = tid >> 6, lane = tid & 63;
    if (lane == 0) sred[wave] = sum;
    __syncthreads();
    if (tid == 0)
        out[0] = (float)((sred[0] + sred[1] + sred[2] + sred[3]) / (double)((size_t)BB * TT));
}

extern "C" void kernel_launch(void* const* d_in, const int* in_sizes, int n_in,
                              void* d_out, int out_size, void* d_ws, size_t ws_size,
                              hipStream_t stream) {
    const float* pred   = (const float*)d_in[0];
    const float* target = (const float*)d_in[1];
    float* out = (float*)d_out;

    // workspace layout: [ partials: 2048 doubles ][ Lbuf/carry: B*K*C floats ]
    double* partials = (double*)d_ws;
    float* Lbuf = (float*)((char*)d_ws + (size_t)BB * KCH * sizeof(double));

    p1_local<<<BB * KCH, BLK, 0, stream>>>(target, Lbuf);
    p2_carry<<<(BB * CC + 255) / 256, 256, 0, stream>>>(target, Lbuf);
    p3_loss<<<BB * KCH, BLK, 0, stream>>>(pred, target, Lbuf, partials);
    p4_final<<<1, 256, 0, stream>>>(partials, out);
}